// Round 1
// baseline (85.696 us; speedup 1.0000x reference)
//
#include <hip/hip_runtime.h>
#include <math.h>

#define Bc 2
#define Hc 32
#define N1c 1024
#define Nc 1023
#define BLOCK 256

__global__ __launch_bounds__(BLOCK) void se3_head_kernel(
    const float* __restrict__ x,    // [B,N,3]
    const float* __restrict__ qk,   // [B,H,N1,N1]
    const float* __restrict__ W1,   // [H,H]
    const float* __restrict__ b1,   // [H]
    const float* __restrict__ W2,   // [1,H]
    const float* __restrict__ b2,   // [1]
    float* __restrict__ out)        // [B,N,3]
{
    const int bi  = blockIdx.x;
    const int b   = bi / Nc;
    const int i   = bi % Nc;
    const int tid = threadIdx.x;

    const float xi0 = x[(b * Nc + i) * 3 + 0];
    const float xi1 = x[(b * Nc + i) * 3 + 1];
    const float xi2 = x[(b * Nc + i) * 3 + 2];
    const float b2v = b2[0];

    // qk[b, h, i+1, j+1] = qk_b[h*N1*N1 + (j+1)]
    const float* qk_b = qk + (size_t)b * Hc * N1c * N1c + (size_t)(i + 1) * N1c;
    const float* xb   = x + (size_t)b * Nc * 3;

    float S = 0.f, T0 = 0.f, T1 = 0.f, T2 = 0.f;

    for (int j = tid; j < Nc; j += BLOCK) {
        // gather q[h] — coalesced across lanes (consecutive j)
        float q[Hc];
        #pragma unroll
        for (int h = 0; h < Hc; ++h) {
            float v = qk_b[(size_t)h * N1c * N1c + (j + 1)];
            q[h] = isinf(v) ? 0.f : v;
        }

        // tiny MLP: c = b2 + sum_g W2[g]*relu(b1[g] + sum_h q[h]*W1[g,h])
        float c = b2v;
        #pragma unroll 4
        for (int g = 0; g < Hc; ++g) {
            float acc = b1[g];  // uniform -> SGPR
            #pragma unroll
            for (int hh = 0; hh < Hc; ++hh)
                acc = fmaf(q[hh], W1[g * Hc + hh], acc);  // W1 uniform -> s_load
            c = fmaf(fmaxf(acc, 0.f), W2[g], c);
        }

        S += c;
        T0 = fmaf(xb[j * 3 + 0], c, T0);
        T1 = fmaf(xb[j * 3 + 1], c, T1);
        T2 = fmaf(xb[j * 3 + 2], c, T2);
    }

    // wave (64-lane) reduction
    #pragma unroll
    for (int off = 32; off > 0; off >>= 1) {
        S  += __shfl_down(S,  off);
        T0 += __shfl_down(T0, off);
        T1 += __shfl_down(T1, off);
        T2 += __shfl_down(T2, off);
    }

    __shared__ float red[4][4];
    const int wid = tid >> 6;
    if ((tid & 63) == 0) {
        red[wid][0] = S;
        red[wid][1] = T0;
        red[wid][2] = T1;
        red[wid][3] = T2;
    }
    __syncthreads();

    if (tid == 0) {
        float s = 0.f, t0 = 0.f, t1 = 0.f, t2 = 0.f;
        #pragma unroll
        for (int w = 0; w < 4; ++w) {
            s  += red[w][0];
            t0 += red[w][1];
            t1 += red[w][2];
            t2 += red[w][3];
        }
        // out = x*(1+S) - T
        out[(b * Nc + i) * 3 + 0] = fmaf(xi0, s, xi0) - t0;
        out[(b * Nc + i) * 3 + 1] = fmaf(xi1, s, xi1) - t1;
        out[(b * Nc + i) * 3 + 2] = fmaf(xi2, s, xi2) - t2;
    }
}

extern "C" void kernel_launch(void* const* d_in, const int* in_sizes, int n_in,
                              void* d_out, int out_size, void* d_ws, size_t ws_size,
                              hipStream_t stream) {
    const float* x  = (const float*)d_in[0];
    const float* qk = (const float*)d_in[1];
    const float* W1 = (const float*)d_in[2];
    const float* b1 = (const float*)d_in[3];
    const float* W2 = (const float*)d_in[4];
    const float* b2 = (const float*)d_in[5];
    float* out = (float*)d_out;

    dim3 grid(Bc * Nc);
    dim3 block(BLOCK);
    se3_head_kernel<<<grid, block, 0, stream>>>(x, qk, W1, b1, W2, b2, out);
}

// Round 2
// 66.110 us; speedup vs baseline: 1.2963x; 1.2963x over previous
//
#include <hip/hip_runtime.h>

#define Bc 2
#define Hc 32
#define N1c 1024
#define Nc 1023
#define BLOCK 256
#define JT 256
#define NTILES 4          // ceil(1023/256)
#define LDSW 40           // padded LDS row width in ushorts (80 B): conflict-free

typedef __attribute__((ext_vector_type(8))) short bf16x8;
typedef __attribute__((ext_vector_type(4))) float f32x4;

// zero +/-inf (reference semantics), then round-to-nearest-even to bf16, pack 2
__device__ __forceinline__ unsigned pack2bf(float a, float b) {
    unsigned ua = __float_as_uint(a), ub = __float_as_uint(b);
    ua = ((ua & 0x7fffffffu) == 0x7f800000u) ? 0u : ua;
    ub = ((ub & 0x7fffffffu) == 0x7f800000u) ? 0u : ub;
    ua = (ua + 0x7fffu + ((ua >> 16) & 1u)) >> 16;
    ub = (ub + 0x7fffu + ((ub >> 16) & 1u)) >> 16;
    return ua | (ub << 16);
}

__device__ __forceinline__ unsigned short f2bf(float a) {
    unsigned ua = __float_as_uint(a);
    ua = (ua + 0x7fffu + ((ua >> 16) & 1u)) >> 16;
    return (unsigned short)ua;
}

__global__ __launch_bounds__(BLOCK) void se3_head_kernel(
    const float* __restrict__ x,    // [B,N,3]
    const float* __restrict__ qk,   // [B,H,N1,N1]
    const float* __restrict__ W1,   // [H,H]
    const float* __restrict__ b1,   // [H]
    const float* __restrict__ W2,   // [1,H]
    const float* __restrict__ b2,   // [1]
    float* __restrict__ out)        // [B,N,3]
{
    __shared__ unsigned short stage[2][JT][LDSW];
    __shared__ float red[4][4];

    const int bi   = blockIdx.x;
    const int b    = bi / Nc;
    const int i    = bi % Nc;
    const int t    = threadIdx.x;
    const int wv   = t >> 6;
    const int lane = t & 63;
    const int lrow = lane & 15;   // A-row / B-col / C-col
    const int lk   = lane >> 4;   // k-chunk / C-row-quad

    const float* qk_b = qk + (size_t)b * Hc * N1c * N1c + (size_t)(i + 1) * N1c;
    const float* xb   = x + (size_t)b * Nc * 3;

    // ---- per-lane constants: B fragments = W1^T (two g-halves), biases ----
    bf16x8 Bf0, Bf1;
    {
        const float* r0 = W1 + lrow * Hc + lk * 8;
        const float* r1 = W1 + (lrow + 16) * Hc + lk * 8;
        #pragma unroll
        for (int e = 0; e < 8; ++e) {
            ((unsigned short*)&Bf0)[e] = f2bf(r0[e]);
            ((unsigned short*)&Bf1)[e] = f2bf(r1[e]);
        }
    }
    const float b1v0 = b1[lrow], b1v1 = b1[lrow + 16];
    const float w2a  = W2[lrow], w2b  = W2[lrow + 16];
    const float b2s  = b2[0] * (1.0f / 16.0f);  // 16 lanes sum per j -> b2

    float S = 0.f, T0 = 0.f, T1 = 0.f, T2 = 0.f;
    float v[Hc];

    auto load_tile = [&](int k) {
        int jj = k * JT + t;
        int js = jj < Nc ? jj : 0;          // clamp; masked in epilogue
        const float* p = qk_b + js + 1;
        #pragma unroll
        for (int h = 0; h < Hc; ++h)
            v[h] = p[(size_t)h * N1c * N1c];   // coalesced in j per h
    };

    auto write_stage = [&](int buf) {
        #pragma unroll
        for (int pq = 0; pq < 4; ++pq) {
            uint4 w;
            w.x = pack2bf(v[pq*8+0], v[pq*8+1]);
            w.y = pack2bf(v[pq*8+2], v[pq*8+3]);
            w.z = pack2bf(v[pq*8+4], v[pq*8+5]);
            w.w = pack2bf(v[pq*8+6], v[pq*8+7]);
            *reinterpret_cast<uint4*>(&stage[buf][t][pq*8]) = w;
        }
    };

    // prologue: stage tile 0
    load_tile(0);
    write_stage(0);
    __syncthreads();

    for (int k = 0; k < NTILES; ++k) {
        if (k + 1 < NTILES) load_tile(k + 1);   // issue early, consume late

        const int buf = k & 1;
        #pragma unroll
        for (int m = 0; m < 4; ++m) {
            const int rbase = wv * 64 + m * 16;
            bf16x8 A = *reinterpret_cast<const bf16x8*>(
                           &stage[buf][rbase + lrow][lk * 8]);
            f32x4 z = {0.f, 0.f, 0.f, 0.f};
            f32x4 c0 = __builtin_amdgcn_mfma_f32_16x16x32_bf16(A, Bf0, z, 0, 0, 0);
            f32x4 c1 = __builtin_amdgcn_mfma_f32_16x16x32_bf16(A, Bf1, z, 0, 0, 0);
            const int jr = k * JT + rbase + lk * 4;
            #pragma unroll
            for (int r = 0; r < 4; ++r) {
                const int j = jr + r;
                float h0 = c0[r] + b1v0;
                float h1 = c1[r] + b1v1;
                float cp = fmaf(fmaxf(h0, 0.f), w2a,
                             fmaf(fmaxf(h1, 0.f), w2b, b2s));
                if (j < Nc) {
                    S += cp;
                    T0 = fmaf(xb[j*3+0], cp, T0);
                    T1 = fmaf(xb[j*3+1], cp, T1);
                    T2 = fmaf(xb[j*3+2], cp, T2);
                }
            }
        }

        if (k + 1 < NTILES) {
            write_stage((k + 1) & 1);
            __syncthreads();
        }
    }

    // ---- block reduction (everything is linear in the per-lane partials) ----
    #pragma unroll
    for (int off = 32; off > 0; off >>= 1) {
        S  += __shfl_down(S,  off);
        T0 += __shfl_down(T0, off);
        T1 += __shfl_down(T1, off);
        T2 += __shfl_down(T2, off);
    }
    if (lane == 0) { red[wv][0] = S; red[wv][1] = T0; red[wv][2] = T1; red[wv][3] = T2; }
    __syncthreads();

    if (t == 0) {
        float s = 0.f, t0 = 0.f, t1 = 0.f, t2 = 0.f;
        #pragma unroll
        for (int w = 0; w < 4; ++w) {
            s += red[w][0]; t0 += red[w][1]; t1 += red[w][2]; t2 += red[w][3];
        }
        const float xi0 = xb[i*3+0], xi1 = xb[i*3+1], xi2 = xb[i*3+2];
        out[(b*Nc+i)*3+0] = fmaf(xi0, s, xi0) - t0;
        out[(b*Nc+i)*3+1] = fmaf(xi1, s, xi1) - t1;
        out[(b*Nc+i)*3+2] = fmaf(xi2, s, xi2) - t2;
    }
}

extern "C" void kernel_launch(void* const* d_in, const int* in_sizes, int n_in,
                              void* d_out, int out_size, void* d_ws, size_t ws_size,
                              hipStream_t stream) {
    const float* x  = (const float*)d_in[0];
    const float* qk = (const float*)d_in[1];
    const float* W1 = (const float*)d_in[2];
    const float* b1 = (const float*)d_in[3];
    const float* W2 = (const float*)d_in[4];
    const float* b2 = (const float*)d_in[5];
    float* out = (float*)d_out;

    se3_head_kernel<<<dim3(Bc * Nc), dim3(BLOCK), 0, stream>>>(
        x, qk, W1, b1, W2, b2, out);
}